// Round 9
// baseline (3679.956 us; speedup 1.0000x reference)
//
#include <hip/hip_runtime.h>
#include <hip/hip_bf16.h>
#include <hip/hip_fp16.h>

#define DIM 32
#define BSHIFT 7            // 128 rows per bucket
#define BROWS 128
#define CAPB 6144           // bsort LDS capacity (mean 4096 edges/bucket, 32-sigma margin)
#define CHUNK 8192          // edges per bin block
#define KMAX 2048           // max buckets (N <= 262144)

// ---------------- bucket build ----------------

__global__ void lgcn_bhist(const int* __restrict__ row,
                           int* __restrict__ bcount, int E, int K) {
    __shared__ int h[KMAX];
    int t = threadIdx.x;
    for (int b = t; b < K; b += blockDim.x) h[b] = 0;
    __syncthreads();
    for (int i = blockIdx.x * blockDim.x + t; i < E; i += gridDim.x * blockDim.x)
        atomicAdd(&h[row[i] >> BSHIFT], 1);
    __syncthreads();
    for (int b = t; b < K; b += blockDim.x)
        if (h[b]) atomicAdd(&bcount[b], h[b]);
}

// Exclusive scan of bucket counts (K <= 2048, 2 slots/thread) -> bbase[0..K],
// bcursor copy.
__global__ void lgcn_bscan(const int* __restrict__ bcount,
                           int* __restrict__ bbase, int* __restrict__ bcursor, int K) {
    __shared__ int s[1024];
    int t = threadIdx.x;
    int i0 = 2 * t, i1 = 2 * t + 1;
    int v0 = (i0 < K) ? bcount[i0] : 0;
    int v1 = (i1 < K) ? bcount[i1] : 0;
    s[t] = v0 + v1;
    __syncthreads();
    for (int off = 1; off < 1024; off <<= 1) {
        int u = (t >= off) ? s[t - off] : 0;
        __syncthreads();
        s[t] += u;
        __syncthreads();
    }
    int excl = s[t] - (v0 + v1);
    if (i0 < K) { bbase[i0] = excl;      bcursor[i0] = excl; }
    if (i1 < K) { bbase[i1] = excl + v0; bcursor[i1] = excl + v0; }
    if (t == 1023) bbase[K] = s[1023];
}

// Bin edges into bucket-clustered order, LDS-sorted per chunk so global writes
// are issued contiguous-in-time per bucket segment. Packs rowlow (7b) in top
// byte (requires N < 2^24).
__launch_bounds__(1024)
__global__ void lgcn_bin(const int* __restrict__ row, const int* __restrict__ col,
                         const float* __restrict__ vals, int* __restrict__ bcursor,
                         int2* __restrict__ binned, int E, int K) {
    __shared__ int hh[KMAX];        // counts -> gdelta
    __shared__ int lb[KMAX + 1];    // local exclusive bases (+ sentinel)
    __shared__ int cur[KMAX];       // scatter cursors
    __shared__ int s[1024];         // scan temp
    __shared__ int2 sbuf[CHUNK];
    int t = threadIdx.x;
    int base = blockIdx.x * CHUNK;
    int cnt = E - base;
    if (cnt > CHUNK) cnt = CHUNK;

    for (int b = t; b < KMAX; b += 1024) hh[b] = 0;
    __syncthreads();

    int  myb[CHUNK / 1024];
    int2 mycv[CHUNK / 1024];
    for (int k = 0; k < CHUNK / 1024; ++k) {
        int i = base + k * 1024 + t;
        if (i < base + cnt) {
            int r = row[i];
            myb[k] = r >> BSHIFT;
            mycv[k] = make_int2(col[i] | ((r & (BROWS - 1)) << 24),
                                __float_as_int(vals[i]));
            atomicAdd(&hh[myb[k]], 1);
        } else myb[k] = -1;
    }
    __syncthreads();

    int v0 = hh[2 * t], v1 = hh[2 * t + 1];
    s[t] = v0 + v1;
    __syncthreads();
    for (int off = 1; off < 1024; off <<= 1) {
        int u = (t >= off) ? s[t - off] : 0;
        __syncthreads();
        s[t] += u;
        __syncthreads();
    }
    int ex = s[t] - (v0 + v1);
    lb[2 * t] = ex;           lb[2 * t + 1] = ex + v0;
    cur[2 * t] = ex;          cur[2 * t + 1] = ex + v0;
    if (t == 1023) lb[KMAX] = s[1023];
    int g0 = v0 ? atomicAdd(&bcursor[2 * t], v0) : 0;
    int g1 = v1 ? atomicAdd(&bcursor[2 * t + 1], v1) : 0;
    hh[2 * t] = g0 - lb[2 * t];
    hh[2 * t + 1] = g1 - lb[2 * t + 1];
    __syncthreads();

    for (int k = 0; k < CHUNK / 1024; ++k) {
        if (myb[k] >= 0) {
            int pos = atomicAdd(&cur[myb[k]], 1);
            sbuf[pos] = mycv[k];
        }
    }
    __syncthreads();

    for (int p = t; p < cnt; p += 1024) {
        int lo = 0, hi = K;        // invariant: lb[lo] <= p < lb[hi]
        while (hi - lo > 1) {
            int mid = (lo + hi) >> 1;
            if (lb[mid] <= p) lo = mid; else hi = mid;
        }
        binned[hh[lo] + p] = sbuf[p];
    }
}

// Per-bucket counting sort by COL-BIN (32 bins, in place). All pull blocks
// then sweep col-space in the same order -> cross-block temporal L2 locality.
// rowlow stays packed in the top byte (pull uses LDS atomics, no row sort).
__global__ void lgcn_bsort(const int* __restrict__ bbase,
                           int2* __restrict__ perm, int cshift) {
    __shared__ int2 sorted[CAPB];
    __shared__ int cnt[32], cur[32];
    int b = blockIdx.x, t = threadIdx.x;
    int sB = bbase[b], eB = bbase[b + 1];
    int nB = eB - sB;
    if (t < 32) cnt[t] = 0;
    __syncthreads();
    for (int i = sB + t; i < eB; i += 256)
        atomicAdd(&cnt[((perm[i].x & 0x00FFFFFF) >> cshift) & 31], 1);
    __syncthreads();
    if (t == 0) {
        int run = 0;
        for (int q = 0; q < 32; ++q) { int c = cnt[q]; cur[q] = run; run += c; }
    }
    __syncthreads();
    for (int i = sB + t; i < eB; i += 256) {
        int2 cv = perm[i];
        int q = ((cv.x & 0x00FFFFFF) >> cshift) & 31;
        int p = atomicAdd(&cur[q], 1);
        if (p < CAPB) sorted[p] = cv;
    }
    __syncthreads();
    for (int p = t; p < nB; p += 256) {
        int pp = p < CAPB ? p : CAPB - 1;              // unreachable clamp
        perm[sB + p] = sorted[pp];
    }
}

// f32 -> f16 convert (gathered operand)
__global__ void lgcn_f2h(const float* __restrict__ src,
                         __half2* __restrict__ dst, int n2) {
    int i = blockIdx.x * blockDim.x + threadIdx.x;
    if (i >= n2) return;
    float2 v = ((const float2*)src)[i];
    dst[i] = __float22half2_rn(v);
}

// ---------------- bucket-resident pull: LDS f32 acc, col-sorted edges ----
// One block per 128-row bucket (16 KB acc), grid ~1563 all co-resident at
// ~6 blocks/CU; 16 edge-slots x 16 lanes x 4-deep => ~384 gathers in
// flight/CU (round-5 MLP) + round-6 col-sweep locality.
// MODE 0: e_next = h(acc); out = emb + acc    (layer 1)
// MODE 1: e_next = h(acc); out += acc         (layer 2)
// MODE 2: out = (out + acc) * 0.25            (layer 3)
template <int MODE>
__launch_bounds__(256, 6)
__global__ void lgcn_pull(const int* __restrict__ bbase,
                          const int2* __restrict__ perm,
                          const __half2* __restrict__ e_cur,
                          __half2* __restrict__ e_next,
                          const float* __restrict__ emb,
                          float* __restrict__ out, int N) {
    __shared__ float acc[BROWS * DIM];                  // 16 KB
    int b = blockIdx.x, t = threadIdx.x;
    for (int i = t; i < BROWS * DIM / 4; i += 256)
        ((float4*)acc)[i] = make_float4(0.f, 0.f, 0.f, 0.f);
    __syncthreads();

    int sB = bbase[b], eB = bbase[b + 1];
    int d2 = t & 15;                                    // half2 dim pair
    int slot = t >> 4;                                  // 16 edge slots
    int p = sB + slot;
    for (; p + 48 < eB; p += 64) {
        int2 c0 = perm[p];
        int2 c1 = perm[p + 16];
        int2 c2 = perm[p + 32];
        int2 c3 = perm[p + 48];
        float2 x0 = __half22float2(e_cur[(size_t)(c0.x & 0x00FFFFFF) * 16 + d2]);
        float2 x1 = __half22float2(e_cur[(size_t)(c1.x & 0x00FFFFFF) * 16 + d2]);
        float2 x2 = __half22float2(e_cur[(size_t)(c2.x & 0x00FFFFFF) * 16 + d2]);
        float2 x3 = __half22float2(e_cur[(size_t)(c3.x & 0x00FFFFFF) * 16 + d2]);
        float v0 = __int_as_float(c0.y), v1 = __int_as_float(c1.y);
        float v2 = __int_as_float(c2.y), v3 = __int_as_float(c3.y);
        int a0 = (int)((unsigned)c0.x >> 24) * DIM + 2 * d2;
        int a1 = (int)((unsigned)c1.x >> 24) * DIM + 2 * d2;
        int a2 = (int)((unsigned)c2.x >> 24) * DIM + 2 * d2;
        int a3 = (int)((unsigned)c3.x >> 24) * DIM + 2 * d2;
        atomicAdd(&acc[a0], v0 * x0.x); atomicAdd(&acc[a0 + 1], v0 * x0.y);
        atomicAdd(&acc[a1], v1 * x1.x); atomicAdd(&acc[a1 + 1], v1 * x1.y);
        atomicAdd(&acc[a2], v2 * x2.x); atomicAdd(&acc[a2 + 1], v2 * x2.y);
        atomicAdd(&acc[a3], v3 * x3.x); atomicAdd(&acc[a3 + 1], v3 * x3.y);
    }
    for (; p < eB; p += 16) {
        int2 cv = perm[p];
        float2 x = __half22float2(e_cur[(size_t)(cv.x & 0x00FFFFFF) * 16 + d2]);
        float v = __int_as_float(cv.y);
        int a = (int)((unsigned)cv.x >> 24) * DIM + 2 * d2;
        atomicAdd(&acc[a], v * x.x); atomicAdd(&acc[a + 1], v * x.y);
    }
    __syncthreads();

    int g0 = b << BSHIFT;
    int rows = N - g0; if (rows > BROWS) rows = BROWS;
    for (int i = t; i < rows * (DIM / 2); i += 256) {   // float2 granularity
        size_t o2 = (size_t)g0 * (DIM / 2) + i;
        float2 a = ((float2*)acc)[i];
        if (MODE == 0) {
            e_next[o2] = __float22half2_rn(a);
            float2 e0 = ((const float2*)emb)[o2];
            ((float2*)out)[o2] = make_float2(e0.x + a.x, e0.y + a.y);
        } else if (MODE == 1) {
            e_next[o2] = __float22half2_rn(a);
            float2 c = ((float2*)out)[o2];
            ((float2*)out)[o2] = make_float2(c.x + a.x, c.y + a.y);
        } else {
            float2 c = ((float2*)out)[o2];
            ((float2*)out)[o2] = make_float2((c.x + a.x) * 0.25f,
                                             (c.y + a.y) * 0.25f);
        }
    }
}

// ---------------- fallback (round-1 verified atomic path) ----------------

__global__ void lgcn_scatter(const float* __restrict__ e_cur,
                             float* __restrict__ e_next,
                             const float* __restrict__ vals,
                             const int* __restrict__ row_idx,
                             const int* __restrict__ col_idx, int E) {
    int g = blockIdx.x * (blockDim.x >> 5) + (threadIdx.x >> 5);
    if (g >= E) return;
    int d = threadIdx.x & 31;
    int c = col_idx[g];
    int r = row_idx[g];
    float v = vals[g];
    atomicAdd(&e_next[(size_t)r * DIM + d], v * e_cur[(size_t)c * DIM + d]);
}

__global__ void lgcn_add_init(const float* __restrict__ a, const float* __restrict__ b,
                              float* __restrict__ out, int n4) {
    int i = blockIdx.x * blockDim.x + threadIdx.x;
    if (i >= n4) return;
    float4 x = ((const float4*)a)[i]; float4 y = ((const float4*)b)[i];
    ((float4*)out)[i] = make_float4(x.x + y.x, x.y + y.y, x.z + y.z, x.w + y.w);
}
__global__ void lgcn_add(const float* __restrict__ b, float* __restrict__ out, int n4) {
    int i = blockIdx.x * blockDim.x + threadIdx.x;
    if (i >= n4) return;
    float4 x = ((float4*)out)[i]; float4 y = ((const float4*)b)[i];
    ((float4*)out)[i] = make_float4(x.x + y.x, x.y + y.y, x.z + y.z, x.w + y.w);
}
__global__ void lgcn_add_scale(const float* __restrict__ b, float* __restrict__ out,
                               int n4, float s) {
    int i = blockIdx.x * blockDim.x + threadIdx.x;
    if (i >= n4) return;
    float4 x = ((float4*)out)[i]; float4 y = ((const float4*)b)[i];
    ((float4*)out)[i] = make_float4((x.x + y.x) * s, (x.y + y.y) * s,
                                    (x.z + y.z) * s, (x.w + y.w) * s);
}

extern "C" void kernel_launch(void* const* d_in, const int* in_sizes, int n_in,
                              void* d_out, int out_size, void* d_ws, size_t ws_size,
                              hipStream_t stream) {
    const float* emb  = (const float*)d_in[0];
    const float* vals = (const float*)d_in[1];
    const int*   row  = (const int*)d_in[2];
    const int*   col  = (const int*)d_in[3];
    // num_layers (d_in[4]) fixed at 3 in the reference.

    const int N = in_sizes[0] / DIM;     // 200000
    const int E = in_sizes[1];           // 6.4M
    float* out  = (float*)d_out;

    const int K = (N + BROWS - 1) >> BSHIFT;           // buckets (~1563)

    // ws layout (4B words):
    //   emb_h[N*DIM/2] | bufA_h[N*DIM/2] | bcount[K] | bbase[K+1] | bcursor[K]
    //   | (8B-align) perm[E] int2
    const size_t hwords = (size_t)N * DIM / 2;
    __half2* emb_h  = (__half2*)d_ws;
    __half2* bufA_h = (__half2*)((int*)d_ws + hwords);
    int*   bcount  = (int*)d_ws + 2 * hwords;
    int*   bbase   = bcount + K;
    int*   bcursor = bbase + (K + 1);
    size_t word_off = (size_t)((bcursor + K) - (int*)d_ws);
    word_off = (word_off + 1) & ~(size_t)1;            // 8B align
    int2*  perm    = (int2*)((int*)d_ws + word_off);
    const size_t needed = (word_off + (size_t)2 * E) * 4;

    const int n4 = N * DIM / 4;
    const int n2 = N * DIM / 2;
    const int add_grid = (n4 + 255) / 256;
    const size_t layer_bytes = (size_t)N * DIM * sizeof(float);

    // col-bin shift: ((N-1) >> cshift) must fit in 32 bins
    int bits = 32 - __builtin_clz((unsigned)(N - 1));
    int cshift = bits > 5 ? bits - 5 : 0;

    const double mean_bucket = (double)E / (double)N * BROWS;
    const bool csr_ok = (ws_size >= needed) && (K <= KMAX) &&
                        (mean_bucket * 1.45 < (double)CAPB) &&
                        (N < (1 << 24)) && (DIM == 32);

    if (!csr_ok) {
        // fallback: round-1 verified atomic push path (f32 buffers alias ws)
        float* bufA = (float*)d_ws;
        float* bufB = bufA + (size_t)N * DIM;
        const int sct_grid = (E + 7) / 8;
        hipMemsetAsync(bufA, 0, layer_bytes, stream);
        lgcn_scatter<<<sct_grid, 256, 0, stream>>>(emb, bufA, vals, row, col, E);
        lgcn_add_init<<<add_grid, 256, 0, stream>>>(emb, bufA, out, n4);
        hipMemsetAsync(bufB, 0, layer_bytes, stream);
        lgcn_scatter<<<sct_grid, 256, 0, stream>>>(bufA, bufB, vals, row, col, E);
        lgcn_add<<<add_grid, 256, 0, stream>>>(bufB, out, n4);
        hipMemsetAsync(bufA, 0, layer_bytes, stream);
        lgcn_scatter<<<sct_grid, 256, 0, stream>>>(bufB, bufA, vals, row, col, E);
        lgcn_add_scale<<<add_grid, 256, 0, stream>>>(bufA, out, n4, 0.25f);
        return;
    }

    // ---- build: bucket-cluster, col-bin sort within bucket, f16 convert ----
    const int bin_grid = (E + CHUNK - 1) / CHUNK;
    hipMemsetAsync(bcount, 0, (size_t)K * sizeof(int), stream);
    lgcn_f2h<<<(n2 + 255) / 256, 256, 0, stream>>>(emb, emb_h, n2);
    lgcn_bhist<<<bin_grid, 256, 0, stream>>>(row, bcount, E, K);
    lgcn_bscan<<<1, 1024, 0, stream>>>(bcount, bbase, bcursor, K);
    lgcn_bin<<<bin_grid, 1024, 0, stream>>>(row, col, vals, bcursor, perm, E, K);
    lgcn_bsort<<<K, 256, 0, stream>>>(bbase, perm, cshift);

    // ---- 3 bucket-resident pull layers (f16 gather, f32 LDS accumulate) ----
    lgcn_pull<0><<<K, 256, 0, stream>>>(bbase, perm, emb_h, bufA_h, emb, out, N);
    lgcn_pull<1><<<K, 256, 0, stream>>>(bbase, perm, bufA_h, emb_h, emb, out, N);
    lgcn_pull<2><<<K, 256, 0, stream>>>(bbase, perm, emb_h, nullptr, emb, out, N);
}

// Round 11
// 536.459 us; speedup vs baseline: 6.8597x; 6.8597x over previous
//
#include <hip/hip_runtime.h>
#include <hip/hip_bf16.h>
#include <hip/hip_fp16.h>

#define DIM 32
#define BSHIFT 8            // 256 rows per bucket
#define BROWS 256
#define CAP 12288           // bsort LDS capacity (mean 8192 edges/bucket, 45-sigma margin)
#define CHUNK 8192          // edges per bin block
#define KMAX 1024           // max buckets supported (N <= 262144)

template <typename T>
__device__ __forceinline__ T ntload(const T* p) { return __builtin_nontemporal_load(p); }

__device__ __forceinline__ float h2f_bits(unsigned short w) {
    __half_raw hr;
    hr.x = w;
    return __half2float(__half(hr));
}
__device__ __forceinline__ unsigned short f2h_bits(float f) {
    __half_raw hr = __half_raw(__float2half(f));
    return hr.x;
}

// ---------------- bucket build ----------------

__global__ void lgcn_bhist(const int* __restrict__ row,
                           int* __restrict__ bcount, int E, int K) {
    __shared__ int h[KMAX];
    int t = threadIdx.x;
    for (int b = t; b < K; b += blockDim.x) h[b] = 0;
    __syncthreads();
    for (int i = blockIdx.x * blockDim.x + t; i < E; i += gridDim.x * blockDim.x)
        atomicAdd(&h[ntload(row + i) >> BSHIFT], 1);
    __syncthreads();
    for (int b = t; b < K; b += blockDim.x)
        if (h[b]) atomicAdd(&bcount[b], h[b]);
}

__global__ void lgcn_bscan(const int* __restrict__ bcount,
                           int* __restrict__ bbase, int* __restrict__ bcursor, int K) {
    __shared__ int s[1024];
    int t = threadIdx.x;
    int v = (t < K) ? bcount[t] : 0;
    s[t] = v;
    __syncthreads();
    for (int off = 1; off < 1024; off <<= 1) {
        int u = (t >= off) ? s[t - off] : 0;
        __syncthreads();
        s[t] += u;
        __syncthreads();
    }
    if (t < K) {
        int excl = s[t] - v;
        bbase[t] = excl;
        bcursor[t] = excl;
    }
    if (t == 0) bbase[K] = s[1023];
}

// Bin edges into bucket-clustered order, LDS-sorted per chunk so global writes
// are issued contiguous-in-time per bucket segment. Packs rowlow in top byte
// of cr (requires N < 2^24); vals converted to f16 here.
__launch_bounds__(1024)
__global__ void lgcn_bin(const int* __restrict__ row, const int* __restrict__ col,
                         const float* __restrict__ vals, int* __restrict__ bcursor,
                         int* __restrict__ bcr, unsigned short* __restrict__ bvh,
                         int E, int K) {
    __shared__ int hh[KMAX];
    __shared__ int lb[KMAX + 1];
    __shared__ int cur[KMAX];
    __shared__ int sbuf_cr[CHUNK];            // 32 KB
    __shared__ unsigned short sbuf_vh[CHUNK]; // 16 KB
    int t = threadIdx.x;
    int base = blockIdx.x * CHUNK;
    int cnt = E - base;
    if (cnt > CHUNK) cnt = CHUNK;

    for (int b = t; b < K; b += 1024) hh[b] = 0;
    __syncthreads();

    int            myb[CHUNK / 1024];
    int            mycr[CHUNK / 1024];
    unsigned short myvh[CHUNK / 1024];
    for (int k = 0; k < CHUNK / 1024; ++k) {
        int i = base + k * 1024 + t;
        if (i < base + cnt) {
            int r = ntload(row + i);
            myb[k] = r >> BSHIFT;
            mycr[k] = ntload(col + i) | ((r & (BROWS - 1)) << 24);
            myvh[k] = f2h_bits(ntload(vals + i));
            atomicAdd(&hh[myb[k]], 1);
        } else myb[k] = -1;
    }
    __syncthreads();

    int v = (t < K) ? hh[t] : 0;
    lb[t] = v;
    __syncthreads();
    for (int off = 1; off < 1024; off <<= 1) {
        int u = (t >= off) ? lb[t - off] : 0;
        __syncthreads();
        lb[t] += u;
        __syncthreads();
    }
    if (t == 0) lb[K] = cnt;
    int excl = lb[t] - v;
    __syncthreads();
    if (t < K) {
        lb[t] = excl;
        cur[t] = excl;
        int gbase = v ? atomicAdd(&bcursor[t], v) : 0;
        hh[t] = gbase - excl;
    }
    __syncthreads();

    for (int k = 0; k < CHUNK / 1024; ++k) {
        if (myb[k] >= 0) {
            int pos = atomicAdd(&cur[myb[k]], 1);
            sbuf_cr[pos] = mycr[k];
            sbuf_vh[pos] = myvh[k];
        }
    }
    __syncthreads();

    for (int p = t; p < cnt; p += 1024) {
        int lo = 0, hi = K;
        while (hi - lo > 1) {
            int mid = (lo + hi) >> 1;
            if (lb[mid] <= p) lo = mid; else hi = mid;
        }
        int g = hh[lo] + p;
        bcr[g] = sbuf_cr[p];
        bvh[g] = sbuf_vh[p];
    }
}

// Per-bucket LDS counting sort (in place) -> row-sorted CSR; emits row_end[].
// Strips the packed rowlow byte from cr.
__global__ void lgcn_bsort(const int* __restrict__ bbase,
                           int* __restrict__ bcr, unsigned short* __restrict__ bvh,
                           int* __restrict__ row_end, int N) {
    __shared__ int sorted_cr[CAP];             // 48 KB
    __shared__ unsigned short sorted_vh[CAP];  // 24 KB
    __shared__ int cnt[BROWS], scn[BROWS], cur[BROWS];
    int b = blockIdx.x, t = threadIdx.x;
    int sB = bbase[b], eB = bbase[b + 1];
    int nB = eB - sB;
    if (t < BROWS) cnt[t] = 0;
    __syncthreads();
    for (int i = sB + t; i < eB; i += 1024)
        atomicAdd(&cnt[(unsigned)ntload(bcr + i) >> 24], 1);
    __syncthreads();
    if (t < BROWS) scn[t] = cnt[t];
    __syncthreads();
    for (int off = 1; off < BROWS; off <<= 1) {
        int u = (t >= off && t < BROWS) ? scn[t - off] : 0;
        __syncthreads();
        if (t < BROWS) scn[t] += u;
        __syncthreads();
    }
    int g0 = b << BSHIFT;
    if (t < BROWS) {
        if (g0 + t < N) row_end[g0 + t] = sB + scn[t];
        cur[t] = scn[t] - cnt[t];
    }
    __syncthreads();
    for (int i = sB + t; i < eB; i += 1024) {
        int cr = bcr[i];
        unsigned short vh = bvh[i];
        int r = (unsigned)cr >> 24;
        int p = atomicAdd(&cur[r], 1);
        if (p < CAP) { sorted_cr[p] = cr; sorted_vh[p] = vh; }
    }
    __syncthreads();
    for (int p = t; p < nB; p += 1024) {
        int pp = p < CAP ? p : CAP - 1;
        bcr[sB + p] = sorted_cr[pp] & 0x00FFFFFF;
        bvh[sB + p] = sorted_vh[pp];
    }
}

// f32 -> f16 convert (gathered operand)
__global__ void lgcn_f2h(const float* __restrict__ src,
                         __half2* __restrict__ dst, int n2) {
    int i = blockIdx.x * blockDim.x + threadIdx.x;
    if (i >= n2) return;
    float2 v = ((const float2*)src)[i];
    dst[i] = __float22half2_rn(v);
}

// ---------------- pull SpMM, f16 gather (64B/row), f32 accumulate ----------------
// 32-lane group per row; sub = lane>>4 handles even/odd edges, d2 = lane&15
// owns half2 dim pair. 8 edges in flight per group. Edge streams (cols/vals)
// are non-temporal so L2 stays reserved for the gather table.
// MODE 0: e_next = h(acc); out = emb + acc    (layer 1)
// MODE 1: e_next = h(acc); out += acc         (layer 2)
// MODE 2: out = (out + acc) * 0.25            (layer 3)
template <int MODE>
__global__ void lgcn_pull(const int* __restrict__ row_end,
                          const int* __restrict__ cols,
                          const unsigned short* __restrict__ vh,
                          const __half2* __restrict__ e_cur,
                          __half2* __restrict__ e_next,
                          const float* __restrict__ emb,
                          float* __restrict__ out, int N) {
    int g = blockIdx.x * (blockDim.x >> 5) + (threadIdx.x >> 5);
    if (g >= N) return;
    int l = threadIdx.x & 31;
    int sub = l >> 4;
    int d2 = l & 15;
    int beg = (g == 0) ? 0 : row_end[g - 1];
    int end = row_end[g];
    float ax = 0.f, ay = 0.f;
    int p = beg + sub;
    for (; p + 6 < end; p += 8) {
        int c0 = ntload(cols + p);
        int c1 = ntload(cols + p + 2);
        int c2 = ntload(cols + p + 4);
        int c3 = ntload(cols + p + 6);
        unsigned short w0 = ntload(vh + p);
        unsigned short w1 = ntload(vh + p + 2);
        unsigned short w2 = ntload(vh + p + 4);
        unsigned short w3 = ntload(vh + p + 6);
        float2 x0 = __half22float2(e_cur[(size_t)c0 * 16 + d2]);
        float2 x1 = __half22float2(e_cur[(size_t)c1 * 16 + d2]);
        float2 x2 = __half22float2(e_cur[(size_t)c2 * 16 + d2]);
        float2 x3 = __half22float2(e_cur[(size_t)c3 * 16 + d2]);
        float v0 = h2f_bits(w0);
        float v1 = h2f_bits(w1);
        float v2 = h2f_bits(w2);
        float v3 = h2f_bits(w3);
        ax = fmaf(v0, x0.x, ax); ay = fmaf(v0, x0.y, ay);
        ax = fmaf(v1, x1.x, ax); ay = fmaf(v1, x1.y, ay);
        ax = fmaf(v2, x2.x, ax); ay = fmaf(v2, x2.y, ay);
        ax = fmaf(v3, x3.x, ax); ay = fmaf(v3, x3.y, ay);
    }
    for (; p < end; p += 2) {
        int c = ntload(cols + p);
        unsigned short w = ntload(vh + p);
        float2 x = __half22float2(e_cur[(size_t)c * 16 + d2]);
        float v = h2f_bits(w);
        ax = fmaf(v, x.x, ax); ay = fmaf(v, x.y, ay);
    }
    ax += __shfl_xor(ax, 16);
    ay += __shfl_xor(ay, 16);
    if (sub == 0) {
        size_t o2 = (size_t)g * 16 + d2;
        if (MODE == 0) {
            e_next[o2] = __float22half2_rn(make_float2(ax, ay));
            float2 e0 = ((const float2*)emb)[o2];
            ((float2*)out)[o2] = make_float2(e0.x + ax, e0.y + ay);
        } else if (MODE == 1) {
            e_next[o2] = __float22half2_rn(make_float2(ax, ay));
            float2 c = ((float2*)out)[o2];
            ((float2*)out)[o2] = make_float2(c.x + ax, c.y + ay);
        } else {
            float2 c = ((float2*)out)[o2];
            ((float2*)out)[o2] = make_float2((c.x + ax) * 0.25f,
                                             (c.y + ay) * 0.25f);
        }
    }
}

// ---------------- fallback (round-1 verified atomic path) ----------------

__global__ void lgcn_scatter(const float* __restrict__ e_cur,
                             float* __restrict__ e_next,
                             const float* __restrict__ vals,
                             const int* __restrict__ row_idx,
                             const int* __restrict__ col_idx, int E) {
    int g = blockIdx.x * (blockDim.x >> 5) + (threadIdx.x >> 5);
    if (g >= E) return;
    int d = threadIdx.x & 31;
    int c = col_idx[g];
    int r = row_idx[g];
    float v = vals[g];
    atomicAdd(&e_next[(size_t)r * DIM + d], v * e_cur[(size_t)c * DIM + d]);
}

__global__ void lgcn_add_init(const float* __restrict__ a, const float* __restrict__ b,
                              float* __restrict__ out, int n4) {
    int i = blockIdx.x * blockDim.x + threadIdx.x;
    if (i >= n4) return;
    float4 x = ((const float4*)a)[i]; float4 y = ((const float4*)b)[i];
    ((float4*)out)[i] = make_float4(x.x + y.x, x.y + y.y, x.z + y.z, x.w + y.w);
}
__global__ void lgcn_add(const float* __restrict__ b, float* __restrict__ out, int n4) {
    int i = blockIdx.x * blockDim.x + threadIdx.x;
    if (i >= n4) return;
    float4 x = ((float4*)out)[i]; float4 y = ((const float4*)b)[i];
    ((float4*)out)[i] = make_float4(x.x + y.x, x.y + y.y, x.z + y.z, x.w + y.w);
}
__global__ void lgcn_add_scale(const float* __restrict__ b, float* __restrict__ out,
                               int n4, float s) {
    int i = blockIdx.x * blockDim.x + threadIdx.x;
    if (i >= n4) return;
    float4 x = ((float4*)out)[i]; float4 y = ((const float4*)b)[i];
    ((float4*)out)[i] = make_float4((x.x + y.x) * s, (x.y + y.y) * s,
                                    (x.z + y.z) * s, (x.w + y.w) * s);
}

extern "C" void kernel_launch(void* const* d_in, const int* in_sizes, int n_in,
                              void* d_out, int out_size, void* d_ws, size_t ws_size,
                              hipStream_t stream) {
    const float* emb  = (const float*)d_in[0];
    const float* vals = (const float*)d_in[1];
    const int*   row  = (const int*)d_in[2];
    const int*   col  = (const int*)d_in[3];
    // num_layers (d_in[4]) fixed at 3 in the reference.

    const int N = in_sizes[0] / DIM;     // 200000
    const int E = in_sizes[1];           // 6.4M
    float* out  = (float*)d_out;

    const int K = (N + BROWS - 1) >> BSHIFT;

    // ws layout (4B words):
    //   emb_h[N*DIM/2] | bufA_h[N*DIM/2] | bufB_h[N*DIM/2] | row_end[N]
    //   | bcount[K] | bbase[K+1] | bcursor[K] | cols[E] | val_h[E/2 words]
    const size_t hwords = (size_t)N * DIM / 2;
    __half2* emb_h  = (__half2*)d_ws;
    __half2* bufA_h = (__half2*)((int*)d_ws + hwords);
    __half2* bufB_h = (__half2*)((int*)d_ws + 2 * hwords);
    int*   row_end = (int*)d_ws + 3 * hwords;
    int*   bcount  = row_end + N;
    int*   bbase   = bcount + K;
    int*   bcursor = bbase + (K + 1);
    int*   colsbuf = bcursor + K;
    unsigned short* vhbuf = (unsigned short*)(colsbuf + E);
    const size_t needed = ((size_t)(colsbuf - (int*)d_ws) + (size_t)E + (E + 1) / 2) * 4;

    const int n4 = N * DIM / 4;
    const int n2 = N * DIM / 2;
    const int add_grid = (n4 + 255) / 256;
    const size_t layer_bytes = (size_t)N * DIM * sizeof(float);

    const double mean_bucket = (double)E / (double)N * BROWS;
    const bool csr_ok = (ws_size >= needed) && (K <= KMAX) &&
                        (mean_bucket * 1.45 < (double)CAP) &&
                        (N < (1 << 24)) && (DIM == 32);

    if (!csr_ok) {
        // fallback: round-1 verified atomic push path (f32 buffers alias ws)
        float* bufA = (float*)d_ws;
        float* bufB = bufA + (size_t)N * DIM;
        const int sct_grid = (E + 7) / 8;
        hipMemsetAsync(bufA, 0, layer_bytes, stream);
        lgcn_scatter<<<sct_grid, 256, 0, stream>>>(emb, bufA, vals, row, col, E);
        lgcn_add_init<<<add_grid, 256, 0, stream>>>(emb, bufA, out, n4);
        hipMemsetAsync(bufB, 0, layer_bytes, stream);
        lgcn_scatter<<<sct_grid, 256, 0, stream>>>(bufA, bufB, vals, row, col, E);
        lgcn_add<<<add_grid, 256, 0, stream>>>(bufB, out, n4);
        hipMemsetAsync(bufA, 0, layer_bytes, stream);
        lgcn_scatter<<<sct_grid, 256, 0, stream>>>(bufB, bufA, vals, row, col, E);
        lgcn_add_scale<<<add_grid, 256, 0, stream>>>(bufA, out, n4, 0.25f);
        return;
    }

    // ---- bucketed CSR build + emb f16 convert ----
    const int bin_grid = (E + CHUNK - 1) / CHUNK;
    hipMemsetAsync(bcount, 0, (size_t)K * sizeof(int), stream);
    lgcn_f2h<<<(n2 + 255) / 256, 256, 0, stream>>>(emb, emb_h, n2);
    lgcn_bhist<<<bin_grid, 256, 0, stream>>>(row, bcount, E, K);
    lgcn_bscan<<<1, 1024, 0, stream>>>(bcount, bbase, bcursor, K);
    lgcn_bin<<<bin_grid, 1024, 0, stream>>>(row, col, vals, bcursor,
                                            colsbuf, vhbuf, E, K);
    lgcn_bsort<<<K, 1024, 0, stream>>>(bbase, colsbuf, vhbuf, row_end, N);

    // ---- 3 pull layers (f16 gather, f32 accumulate) ----
    const int pull_grid = (N + 7) / 8;
    lgcn_pull<0><<<pull_grid, 256, 0, stream>>>(row_end, colsbuf, vhbuf,
                                                emb_h, bufA_h, emb, out, N);
    lgcn_pull<1><<<pull_grid, 256, 0, stream>>>(row_end, colsbuf, vhbuf,
                                                bufA_h, bufB_h, emb, out, N);
    lgcn_pull<2><<<pull_grid, 256, 0, stream>>>(row_end, colsbuf, vhbuf,
                                                bufB_h, nullptr, emb, out, N);
}

// Round 12
// 454.634 us; speedup vs baseline: 8.0943x; 1.1800x over previous
//
#include <hip/hip_runtime.h>
#include <hip/hip_bf16.h>
#include <hip/hip_fp16.h>

#define DIM 32
#define BSHIFT 8            // 256 rows per bucket
#define BROWS 256
#define CAP 12288           // bsort LDS capacity (mean 8192 edges/bucket, 45-sigma margin)
#define CHUNK 8192          // edges per bin block
#define KMAX 1024           // max buckets supported (N <= 262144)

// ---------------- bucket build ----------------

__global__ void lgcn_bhist(const int* __restrict__ row,
                           int* __restrict__ bcount, int E, int K) {
    __shared__ int h[KMAX];
    int t = threadIdx.x;
    for (int b = t; b < K; b += blockDim.x) h[b] = 0;
    __syncthreads();
    for (int i = blockIdx.x * blockDim.x + t; i < E; i += gridDim.x * blockDim.x)
        atomicAdd(&h[row[i] >> BSHIFT], 1);
    __syncthreads();
    for (int b = t; b < K; b += blockDim.x)
        if (h[b]) atomicAdd(&bcount[b], h[b]);
}

__global__ void lgcn_bscan(const int* __restrict__ bcount,
                           int* __restrict__ bbase, int* __restrict__ bcursor, int K) {
    __shared__ int s[1024];
    int t = threadIdx.x;
    int v = (t < K) ? bcount[t] : 0;
    s[t] = v;
    __syncthreads();
    for (int off = 1; off < 1024; off <<= 1) {
        int u = (t >= off) ? s[t - off] : 0;
        __syncthreads();
        s[t] += u;
        __syncthreads();
    }
    if (t < K) {
        int excl = s[t] - v;
        bbase[t] = excl;
        bcursor[t] = excl;
    }
    if (t == 0) bbase[K] = s[1023];
}

// Bin edges into bucket-clustered order, LDS-sorted per chunk so global writes
// are issued contiguous-in-time per bucket segment. Packs rowlow in top byte
// (requires N < 2^24).
__launch_bounds__(1024)
__global__ void lgcn_bin(const int* __restrict__ row, const int* __restrict__ col,
                         const float* __restrict__ vals, int* __restrict__ bcursor,
                         int2* __restrict__ binned, int E, int K) {
    __shared__ int hh[KMAX];
    __shared__ int lb[KMAX + 1];
    __shared__ int cur[KMAX];
    __shared__ int2 sbuf[CHUNK];
    int t = threadIdx.x;
    int base = blockIdx.x * CHUNK;
    int cnt = E - base;
    if (cnt > CHUNK) cnt = CHUNK;

    for (int b = t; b < K; b += 1024) hh[b] = 0;
    __syncthreads();

    int  myb[CHUNK / 1024];
    int2 mycv[CHUNK / 1024];
    for (int k = 0; k < CHUNK / 1024; ++k) {
        int i = base + k * 1024 + t;
        if (i < base + cnt) {
            int r = row[i];
            myb[k] = r >> BSHIFT;
            mycv[k] = make_int2(col[i] | ((r & (BROWS - 1)) << 24),
                                __float_as_int(vals[i]));
            atomicAdd(&hh[myb[k]], 1);
        } else myb[k] = -1;
    }
    __syncthreads();

    int v = (t < K) ? hh[t] : 0;
    lb[t] = v;
    __syncthreads();
    for (int off = 1; off < 1024; off <<= 1) {
        int u = (t >= off) ? lb[t - off] : 0;
        __syncthreads();
        lb[t] += u;
        __syncthreads();
    }
    if (t == 0) lb[K] = cnt;
    int excl = lb[t] - v;
    __syncthreads();
    if (t < K) {
        lb[t] = excl;
        cur[t] = excl;
        int gbase = v ? atomicAdd(&bcursor[t], v) : 0;
        hh[t] = gbase - excl;
    }
    __syncthreads();

    for (int k = 0; k < CHUNK / 1024; ++k) {
        if (myb[k] >= 0) {
            int pos = atomicAdd(&cur[myb[k]], 1);
            sbuf[pos] = mycv[k];
        }
    }
    __syncthreads();

    for (int p = t; p < cnt; p += 1024) {
        int lo = 0, hi = K;
        while (hi - lo > 1) {
            int mid = (lo + hi) >> 1;
            if (lb[mid] <= p) lo = mid; else hi = mid;
        }
        binned[hh[lo] + p] = sbuf[p];
    }
}

// Per-bucket LDS counting sort (in place) -> row-sorted CSR; emits row_end[].
__global__ void lgcn_bsort(const int* __restrict__ bbase,
                           int2* __restrict__ perm,
                           int* __restrict__ row_end, int N) {
    __shared__ int2 sorted[CAP];
    __shared__ int cnt[BROWS], scn[BROWS], cur[BROWS];
    int b = blockIdx.x, t = threadIdx.x;
    int sB = bbase[b], eB = bbase[b + 1];
    int nB = eB - sB;
    if (t < BROWS) cnt[t] = 0;
    __syncthreads();
    for (int i = sB + t; i < eB; i += 1024)
        atomicAdd(&cnt[(unsigned)perm[i].x >> 24], 1);
    __syncthreads();
    if (t < BROWS) scn[t] = cnt[t];
    __syncthreads();
    for (int off = 1; off < BROWS; off <<= 1) {
        int u = (t >= off && t < BROWS) ? scn[t - off] : 0;
        __syncthreads();
        if (t < BROWS) scn[t] += u;
        __syncthreads();
    }
    int g0 = b << BSHIFT;
    if (t < BROWS) {
        if (g0 + t < N) row_end[g0 + t] = sB + scn[t];
        cur[t] = scn[t] - cnt[t];
    }
    __syncthreads();
    for (int i = sB + t; i < eB; i += 1024) {
        int2 cv = perm[i];
        int r = (unsigned)cv.x >> 24;
        int p = atomicAdd(&cur[r], 1);
        if (p < CAP) sorted[p] = cv;
    }
    __syncthreads();
    for (int p = t; p < nB; p += 1024) {
        int pp = p < CAP ? p : CAP - 1;
        int2 cv = sorted[pp];
        perm[sB + p] = make_int2(cv.x & 0x00FFFFFF, cv.y);
    }
}

// f32 -> f16 convert (gathered operand)
__global__ void lgcn_f2h(const float* __restrict__ src,
                         __half2* __restrict__ dst, int n2) {
    int i = blockIdx.x * blockDim.x + threadIdx.x;
    if (i >= n2) return;
    float2 v = ((const float2*)src)[i];
    dst[i] = __float22half2_rn(v);
}

// ---------------- pull SpMM, f16 gather (64B/row), f32 accumulate ----------------
// 32-lane group per row; sub = lane>>4 handles even/odd edges, d2 = lane&15
// owns half2 dim pair. 8 edges in flight per group.
// MODE 0: e_next = h(acc); out = emb + acc    (layer 1)
// MODE 1: e_next = h(acc); out += acc         (layer 2)
// MODE 2: out = (out + acc) * 0.25            (layer 3)
template <int MODE>
__global__ void lgcn_pull(const int* __restrict__ row_end,
                          const int2* __restrict__ perm,
                          const __half2* __restrict__ e_cur,
                          __half2* __restrict__ e_next,
                          const float* __restrict__ emb,
                          float* __restrict__ out, int N) {
    int g = blockIdx.x * (blockDim.x >> 5) + (threadIdx.x >> 5);
    if (g >= N) return;
    int l = threadIdx.x & 31;
    int sub = l >> 4;
    int d2 = l & 15;
    int beg = (g == 0) ? 0 : row_end[g - 1];
    int end = row_end[g];
    float ax = 0.f, ay = 0.f;
    int p = beg + sub;
    for (; p + 6 < end; p += 8) {
        int2 c0 = perm[p];
        int2 c1 = perm[p + 2];
        int2 c2 = perm[p + 4];
        int2 c3 = perm[p + 6];
        float2 x0 = __half22float2(e_cur[(size_t)c0.x * 16 + d2]);
        float2 x1 = __half22float2(e_cur[(size_t)c1.x * 16 + d2]);
        float2 x2 = __half22float2(e_cur[(size_t)c2.x * 16 + d2]);
        float2 x3 = __half22float2(e_cur[(size_t)c3.x * 16 + d2]);
        float v0 = __int_as_float(c0.y), v1 = __int_as_float(c1.y);
        float v2 = __int_as_float(c2.y), v3 = __int_as_float(c3.y);
        ax = fmaf(v0, x0.x, ax); ay = fmaf(v0, x0.y, ay);
        ax = fmaf(v1, x1.x, ax); ay = fmaf(v1, x1.y, ay);
        ax = fmaf(v2, x2.x, ax); ay = fmaf(v2, x2.y, ay);
        ax = fmaf(v3, x3.x, ax); ay = fmaf(v3, x3.y, ay);
    }
    for (; p < end; p += 2) {
        int2 cv = perm[p];
        float2 x = __half22float2(e_cur[(size_t)cv.x * 16 + d2]);
        float v = __int_as_float(cv.y);
        ax = fmaf(v, x.x, ax); ay = fmaf(v, x.y, ay);
    }
    ax += __shfl_xor(ax, 16);
    ay += __shfl_xor(ay, 16);
    if (sub == 0) {
        size_t o2 = (size_t)g * 16 + d2;
        if (MODE == 0) {
            e_next[o2] = __float22half2_rn(make_float2(ax, ay));
            float2 e0 = ((const float2*)emb)[o2];
            ((float2*)out)[o2] = make_float2(e0.x + ax, e0.y + ay);
        } else if (MODE == 1) {
            e_next[o2] = __float22half2_rn(make_float2(ax, ay));
            float2 c = ((float2*)out)[o2];
            ((float2*)out)[o2] = make_float2(c.x + ax, c.y + ay);
        } else {
            float2 c = ((float2*)out)[o2];
            ((float2*)out)[o2] = make_float2((c.x + ax) * 0.25f,
                                             (c.y + ay) * 0.25f);
        }
    }
}

// ---------------- fallback (round-1 verified atomic path) ----------------

__global__ void lgcn_scatter(const float* __restrict__ e_cur,
                             float* __restrict__ e_next,
                             const float* __restrict__ vals,
                             const int* __restrict__ row_idx,
                             const int* __restrict__ col_idx, int E) {
    int g = blockIdx.x * (blockDim.x >> 5) + (threadIdx.x >> 5);
    if (g >= E) return;
    int d = threadIdx.x & 31;
    int c = col_idx[g];
    int r = row_idx[g];
    float v = vals[g];
    atomicAdd(&e_next[(size_t)r * DIM + d], v * e_cur[(size_t)c * DIM + d]);
}

__global__ void lgcn_add_init(const float* __restrict__ a, const float* __restrict__ b,
                              float* __restrict__ out, int n4) {
    int i = blockIdx.x * blockDim.x + threadIdx.x;
    if (i >= n4) return;
    float4 x = ((const float4*)a)[i]; float4 y = ((const float4*)b)[i];
    ((float4*)out)[i] = make_float4(x.x + y.x, x.y + y.y, x.z + y.z, x.w + y.w);
}
__global__ void lgcn_add(const float* __restrict__ b, float* __restrict__ out, int n4) {
    int i = blockIdx.x * blockDim.x + threadIdx.x;
    if (i >= n4) return;
    float4 x = ((float4*)out)[i]; float4 y = ((const float4*)b)[i];
    ((float4*)out)[i] = make_float4(x.x + y.x, x.y + y.y, x.z + y.z, x.w + y.w);
}
__global__ void lgcn_add_scale(const float* __restrict__ b, float* __restrict__ out,
                               int n4, float s) {
    int i = blockIdx.x * blockDim.x + threadIdx.x;
    if (i >= n4) return;
    float4 x = ((float4*)out)[i]; float4 y = ((const float4*)b)[i];
    ((float4*)out)[i] = make_float4((x.x + y.x) * s, (x.y + y.y) * s,
                                    (x.z + y.z) * s, (x.w + y.w) * s);
}

extern "C" void kernel_launch(void* const* d_in, const int* in_sizes, int n_in,
                              void* d_out, int out_size, void* d_ws, size_t ws_size,
                              hipStream_t stream) {
    const float* emb  = (const float*)d_in[0];
    const float* vals = (const float*)d_in[1];
    const int*   row  = (const int*)d_in[2];
    const int*   col  = (const int*)d_in[3];
    // num_layers (d_in[4]) fixed at 3 in the reference.

    const int N = in_sizes[0] / DIM;     // 200000
    const int E = in_sizes[1];           // 6.4M
    float* out  = (float*)d_out;

    const int K = (N + BROWS - 1) >> BSHIFT;

    // ws layout (4B words):
    //   emb_h[N*DIM/2] | bufA_h[N*DIM/2] | bufB_h[N*DIM/2] | row_end[N]
    //   | bcount[K] | bbase[K+1] | bcursor[K] | (8B-align) perm[E] int2
    const size_t hwords = (size_t)N * DIM / 2;
    __half2* emb_h  = (__half2*)d_ws;
    __half2* bufA_h = (__half2*)((int*)d_ws + hwords);
    __half2* bufB_h = (__half2*)((int*)d_ws + 2 * hwords);
    int*   row_end = (int*)d_ws + 3 * hwords;
    int*   bcount  = row_end + N;
    int*   bbase   = bcount + K;
    int*   bcursor = bbase + (K + 1);
    size_t word_off = (size_t)((bcursor + K) - (int*)d_ws);
    word_off = (word_off + 1) & ~(size_t)1;           // 8B align
    int2*  perm    = (int2*)((int*)d_ws + word_off);
    const size_t needed = (word_off + (size_t)2 * E) * 4;

    const int n4 = N * DIM / 4;
    const int n2 = N * DIM / 2;
    const int add_grid = (n4 + 255) / 256;
    const size_t layer_bytes = (size_t)N * DIM * sizeof(float);

    const double mean_bucket = (double)E / (double)N * BROWS;
    const bool csr_ok = (ws_size >= needed) && (K <= KMAX) &&
                        (mean_bucket * 1.45 < (double)CAP) &&
                        (N < (1 << 24)) && (DIM == 32);

    if (!csr_ok) {
        // fallback: round-1 verified atomic push path (f32 buffers alias ws)
        float* bufA = (float*)d_ws;
        float* bufB = bufA + (size_t)N * DIM;
        const int sct_grid = (E + 7) / 8;
        hipMemsetAsync(bufA, 0, layer_bytes, stream);
        lgcn_scatter<<<sct_grid, 256, 0, stream>>>(emb, bufA, vals, row, col, E);
        lgcn_add_init<<<add_grid, 256, 0, stream>>>(emb, bufA, out, n4);
        hipMemsetAsync(bufB, 0, layer_bytes, stream);
        lgcn_scatter<<<sct_grid, 256, 0, stream>>>(bufA, bufB, vals, row, col, E);
        lgcn_add<<<add_grid, 256, 0, stream>>>(bufB, out, n4);
        hipMemsetAsync(bufA, 0, layer_bytes, stream);
        lgcn_scatter<<<sct_grid, 256, 0, stream>>>(bufB, bufA, vals, row, col, E);
        lgcn_add_scale<<<add_grid, 256, 0, stream>>>(bufA, out, n4, 0.25f);
        return;
    }

    // ---- bucketed CSR build + emb f16 convert ----
    const int bin_grid = (E + CHUNK - 1) / CHUNK;
    hipMemsetAsync(bcount, 0, (size_t)K * sizeof(int), stream);
    lgcn_f2h<<<(n2 + 255) / 256, 256, 0, stream>>>(emb, emb_h, n2);
    lgcn_bhist<<<bin_grid, 256, 0, stream>>>(row, bcount, E, K);
    lgcn_bscan<<<1, 1024, 0, stream>>>(bcount, bbase, bcursor, K);
    lgcn_bin<<<bin_grid, 1024, 0, stream>>>(row, col, vals, bcursor, perm, E, K);
    lgcn_bsort<<<K, 1024, 0, stream>>>(bbase, perm, row_end, N);

    // ---- 3 pull layers (f16 gather, f32 accumulate) ----
    const int pull_grid = (N + 7) / 8;
    lgcn_pull<0><<<pull_grid, 256, 0, stream>>>(row_end, perm, emb_h, bufA_h, emb, out, N);
    lgcn_pull<1><<<pull_grid, 256, 0, stream>>>(row_end, perm, bufA_h, bufB_h, emb, out, N);
    lgcn_pull<2><<<pull_grid, 256, 0, stream>>>(row_end, perm, bufB_h, nullptr, emb, out, N);
}